// Round 10
// baseline (158.230 us; speedup 1.0000x reference)
//
#include <hip/hip_runtime.h>

#define B_IMG 8
#define A_TOTAL 120000
#define C_CLS 80
#define M_ANN 32
#define APB 512                        // anchors per block (2 half-tiles of 256)
#define THREADS 256
#define NBLK_X 235                     // ceil(120000/512); tail tile has 192 anchors
#define NBLK   (NBLK_X * B_IMG)        // 1880 blocks
#define NEG075LN2 (-0.51986038542f)    // -0.75 * ln(2)

typedef float f32x4 __attribute__((ext_vector_type(4)));

__device__ __forceinline__ f32x4 ntload(const f32x4* p) {
    return __builtin_nontemporal_load(p);   // streaming read: nt cache hint
}

// ws layout (floats):
//   [0      .. NBLK)    per-block c partial   (rewritten every call)
//   [NBLK   .. 2*NBLK)  per-block r partial
//   [2*NBLK .. 3*NBLK)  per-block n partial
//   [3*NBLK]            completion counter (zeroed by hipMemsetAsync each call)

// One anchor's assignment + (if positive) GIoU + focal correction. Returns m.
__device__ __forceinline__ float phase1_anchor(
    int b, int a, bool valid,
    const float* __restrict__ cls, const float* __restrict__ reg,
    const float* __restrict__ anchors, const float* __restrict__ annb,
    float& c_acc, float& r_acc, float& n_acc)
{
    float mval = 0.0f;
    if (valid) {
        float4 anc = ((const float4*)anchors)[a];
        float ay1 = anc.x, ax1 = anc.y, ay2 = anc.z, ax2 = anc.w;
        float area_a = (ay2 - ay1) * (ax2 - ax1);
        float binter = 0.0f, bua = 1.0f;
        int   barg = 0;
        #pragma unroll
        for (int j = 0; j < M_ANN; ++j) {
            float bx1 = annb[j * 5 + 0], by1 = annb[j * 5 + 1];
            float bx2 = annb[j * 5 + 2], by2 = annb[j * 5 + 3];
            float iw = fmaxf(fminf(ax2, bx2) - fmaxf(ax1, bx1), 0.0f);
            float ih = fmaxf(fminf(ay2, by2) - fmaxf(ay1, by1), 0.0f);
            float inter = iw * ih;
            float ua = fmaxf(area_a + (bx2 - bx1) * (by2 - by1) - inter, 1e-8f);
            bool gt = inter * bua > binter * ua;   // iou_j > iou_best, division-free
            binter = gt ? inter : binter;
            bua    = gt ? ua    : bua;
            barg   = gt ? j     : barg;            // strict > keeps FIRST max
        }
        bool pos = binter >= 0.5f * bua;
        bool neg = binter <  0.4f * bua;
        mval = (pos || neg) ? NEG075LN2 : 0.0f;    // ignore band -> 0

        if (pos) {
            n_acc += 1.0f;
            int k = (int)annb[barg * 5 + 4];
            float cv = cls[((size_t)b * A_TOTAL + a) * C_CLS + k];
            float c  = fminf(fmaxf(cv, 5e-4f), 1.0f - 5e-4f);
            float omc = 1.0f - c;
            c_acc += 0.25f * omc * omc * (-__logf(c))
                   - 0.75f * c * c * (-__logf(omc));

            float4 rg = ((const float4*)reg)[(size_t)b * A_TOTAL + a];
            float ty = rg.x, tx = rg.y, th = rg.z, tw = rg.w;
            float aw = ax2 - ax1, ah = ay2 - ay1;
            float acx = ax1 + 0.5f * aw, acy = ay1 + 0.5f * ah;
            float pcx = tx * aw + acx, pcy = ty * ah + acy;
            float pw = __expf(tw) * aw, ph = __expf(th) * ah;
            float px1 = fmaxf(pcx - 0.5f * pw, 0.0f);
            float py1 = fmaxf(pcy - 0.5f * ph, 0.0f);
            float px2 = fmaxf(pcx + 0.5f * pw, 0.0f);
            float py2 = fmaxf(pcy + 0.5f * ph, 0.0f);
            float gx1 = fmaxf(annb[barg * 5 + 0], 0.0f);
            float gy1 = fmaxf(annb[barg * 5 + 1], 0.0f);
            float gx2 = fmaxf(annb[barg * 5 + 2], 0.0f);
            float gy2 = fmaxf(annb[barg * 5 + 3], 0.0f);
            float iw2 = fmaxf(fminf(px2, gx2) - fmaxf(px1, gx1), 0.0f);
            float ih2 = fmaxf(fminf(py2, gy2) - fmaxf(py1, gy1), 0.0f);
            float inter2 = iw2 * ih2;
            float area_p = fmaxf((px2 - px1) * (py2 - py1), 1e-6f);
            float area_g = fmaxf((gx2 - gx1) * (gy2 - gy1), 1e-6f);
            float uni = area_p + area_g - inter2;
            float iou2 = inter2 / (uni + 1e-7f);
            float wc = fmaxf(fmaxf(px2, gx2) - fminf(px1, gx1), 1e-6f);
            float hc = fmaxf(fmaxf(py2, gy2) - fminf(py1, gy1), 1e-6f);
            float area_c = wc * hc;
            float giou = fminf(fmaxf(iou2 - (area_c - uni) / (area_c + 1e-7f), -1.0f), 1.0f);
            r_acc += 1.0f - giou;
        }
    }
    return mval;
}

__global__ __launch_bounds__(THREADS) void focal_main_kernel(
    const float* __restrict__ cls,      // (B, A, C)
    const float* __restrict__ reg,      // (B, A, 4)
    const float* __restrict__ anchors,  // (A, 4)  [y1,x1,y2,x2]
    const float* __restrict__ ann,      // (B, M, 5) [x1,y1,x2,y2,class]
    float* __restrict__ ws,
    float* __restrict__ out)
{
    __shared__ float m_s[APB];
    __shared__ float red_c[4], red_r[4], red_n[4];
    __shared__ int   lastflag;

    const int b   = blockIdx.y;
    const int a0  = blockIdx.x * APB;
    const int tid = threadIdx.x;
    const int nA  = min(APB, A_TOTAL - a0);       // 512 or 192 (tail)
    const bool full = (nA == APB);
    const float* __restrict__ annb = ann + b * (M_ANN * 5);  // uniform -> s_load

    float r_acc = 0.0f, n_acc = 0.0f, c_acc = 0.0f;

    const f32x4* __restrict__ cp =
        (const f32x4*)(cls + ((size_t)b * A_TOTAL + a0) * C_CLS);

    // ---- Issue group-0 streaming loads FIRST (independent of phase 1) ----
    f32x4 v0, v1, v2, v3, v4, v5, v6, v7, v8, v9;
    if (full) {
        v0 = ntload(cp + tid);
        v1 = ntload(cp + tid + 256);
        v2 = ntload(cp + tid + 512);
        v3 = ntload(cp + tid + 768);
        v4 = ntload(cp + tid + 1024);
        v5 = ntload(cp + tid + 1280);
        v6 = ntload(cp + tid + 1536);
        v7 = ntload(cp + tid + 1792);
        v8 = ntload(cp + tid + 2048);
        v9 = ntload(cp + tid + 2304);
    }

    // ---- Phase 1: two anchors per thread (tid, tid+256) ----
    float m0 = phase1_anchor(b, a0 + tid, tid < nA,
                             cls, reg, anchors, annb, c_acc, r_acc, n_acc);
    float m1 = phase1_anchor(b, a0 + 256 + tid, 256 + tid < nA,
                             cls, reg, anchors, annb, c_acc, r_acc, n_acc);
    m_s[tid]       = m0;
    m_s[tid + 256] = m1;
    __syncthreads();

#define FOCAL4(v, l)                                                      \
    {                                                                     \
        float m_ = m_s[(unsigned)(l) / 20u];                              \
        float s_, c_;                                                     \
        c_ = fminf(fmaxf((v)[0], 5e-4f), 1.0f - 5e-4f);                   \
        s_ = c_ * c_ * __log2f(1.0f - c_);                                \
        c_ = fminf(fmaxf((v)[1], 5e-4f), 1.0f - 5e-4f);                   \
        s_ = fmaf(c_ * c_, __log2f(1.0f - c_), s_);                       \
        c_ = fminf(fmaxf((v)[2], 5e-4f), 1.0f - 5e-4f);                   \
        s_ = fmaf(c_ * c_, __log2f(1.0f - c_), s_);                       \
        c_ = fminf(fmaxf((v)[3], 5e-4f), 1.0f - 5e-4f);                   \
        s_ = fmaf(c_ * c_, __log2f(1.0f - c_), s_);                       \
        c_acc = fmaf(m_, s_, c_acc);                                      \
    }

    if (full) {
        // group 0: consume the pre-issued loads
        FOCAL4(v0, tid)
        FOCAL4(v1, tid + 256)
        FOCAL4(v2, tid + 512)
        FOCAL4(v3, tid + 768)
        FOCAL4(v4, tid + 1024)
        FOCAL4(v5, tid + 1280)
        FOCAL4(v6, tid + 1536)
        FOCAL4(v7, tid + 1792)
        FOCAL4(v8, tid + 2048)
        FOCAL4(v9, tid + 2304)
        // groups 1..3: 10 deep loads each, then consume
        #pragma unroll
        for (int g = 1; g < 4; ++g) {
            const int base = tid + g * 2560;
            v0 = ntload(cp + base);
            v1 = ntload(cp + base + 256);
            v2 = ntload(cp + base + 512);
            v3 = ntload(cp + base + 768);
            v4 = ntload(cp + base + 1024);
            v5 = ntload(cp + base + 1280);
            v6 = ntload(cp + base + 1536);
            v7 = ntload(cp + base + 1792);
            v8 = ntload(cp + base + 2048);
            v9 = ntload(cp + base + 2304);
            FOCAL4(v0, base)
            FOCAL4(v1, base + 256)
            FOCAL4(v2, base + 512)
            FOCAL4(v3, base + 768)
            FOCAL4(v4, base + 1024)
            FOCAL4(v5, base + 1280)
            FOCAL4(v6, base + 1536)
            FOCAL4(v7, base + 1792)
            FOCAL4(v8, base + 2048)
            FOCAL4(v9, base + 2304)
        }
    } else {
        // tail tile: 192 anchors -> 3840 float4, 15 strided iterations
        const int nf4 = nA * (C_CLS / 4);
        for (int l = tid; l < nf4; l += THREADS) {
            f32x4 v = ntload(cp + l);
            FOCAL4(v, l)
        }
    }
#undef FOCAL4

    // ---- Block reduction + NON-ATOMIC per-block slot write ----
    #pragma unroll
    for (int o = 32; o > 0; o >>= 1) {
        c_acc += __shfl_down(c_acc, o);
        r_acc += __shfl_down(r_acc, o);
        n_acc += __shfl_down(n_acc, o);
    }
    int wid = tid >> 6;
    if ((tid & 63) == 0) { red_c[wid] = c_acc; red_r[wid] = r_acc; red_n[wid] = n_acc; }
    __syncthreads();
    if (tid == 0) {
        const int slot = b * NBLK_X + blockIdx.x;
        ws[slot]            = red_c[0] + red_c[1] + red_c[2] + red_c[3];
        ws[NBLK + slot]     = red_r[0] + red_r[1] + red_r[2] + red_r[3];
        ws[2 * NBLK + slot] = red_n[0] + red_n[1] + red_n[2] + red_n[3];
        __threadfence();                                  // release partials (device scope)
        unsigned t = atomicAdd((unsigned*)(ws + 3 * NBLK), 1u);
        lastflag = (t == (unsigned)(NBLK - 1)) ? 1 : 0;   // last block to finish?
    }
    __syncthreads();

    // ---- Last block: in-place finalize (rocPRIM single-pass pattern) ----
    if (lastflag) {
        __threadfence();                // acquire: see all other blocks' partials
        __shared__ float sc[B_IMG], sr[B_IMG], sn[B_IMG];
        const int img    = tid >> 5;    // 0..7
        const int lane32 = tid & 31;

        float pc = 0.0f, pr = 0.0f, pn = 0.0f;
        for (int i = lane32; i < NBLK_X; i += 32) {
            const int slot = img * NBLK_X + i;
            pc += ws[slot];
            pr += ws[NBLK + slot];
            pn += ws[2 * NBLK + slot];
        }
        #pragma unroll
        for (int o = 16; o > 0; o >>= 1) {
            pc += __shfl_down(pc, o, 32);
            pr += __shfl_down(pr, o, 32);
            pn += __shfl_down(pn, o, 32);
        }
        if (lane32 == 0) { sc[img] = pc; sr[img] = pr; sn[img] = pn; }
        __syncthreads();
        if (tid == 0) {
            float c_tot = 0.0f, r_tot = 0.0f;
            #pragma unroll
            for (int bb = 0; bb < B_IMG; ++bb) {
                float ns = sn[bb];
                c_tot += sc[bb] / fmaxf(ns, 1.0f);
                r_tot += (ns > 0.0f) ? (sr[bb] / fmaxf(ns, 1.0f)) : 0.0f;
            }
            c_tot *= (1.0f / B_IMG);
            r_tot *= (1.0f / B_IMG);
            out[0] = c_tot + r_tot;
            out[1] = c_tot;
            out[2] = r_tot;
        }
    }
}

extern "C" void kernel_launch(void* const* d_in, const int* in_sizes, int n_in,
                              void* d_out, int out_size, void* d_ws, size_t ws_size,
                              hipStream_t stream) {
    const float* cls     = (const float*)d_in[0];
    const float* reg     = (const float*)d_in[1];
    const float* anchors = (const float*)d_in[2];
    const float* ann     = (const float*)d_in[3];
    float* ws  = (float*)d_ws;
    float* out = (float*)d_out;

    // zero the completion counter (graph-capture-legal async memset, 4 bytes)
    hipMemsetAsync(ws + 3 * NBLK, 0, sizeof(unsigned), stream);
    dim3 grid(NBLK_X, B_IMG);
    hipLaunchKernelGGL(focal_main_kernel, grid, dim3(THREADS), 0, stream,
                       cls, reg, anchors, ann, ws, out);
}

// Round 11
// 61.579 us; speedup vs baseline: 2.5696x; 2.5696x over previous
//
#include <hip/hip_runtime.h>

#define B_IMG 8
#define A_TOTAL 120000
#define C_CLS 80
#define M_ANN 32
#define APB 512                        // anchors per block (2 half-tiles of 256)
#define THREADS 256
#define NBLK_X 235                     // ceil(120000/512); tail tile has 192 anchors
#define NBLK   (NBLK_X * B_IMG)        // 1880 blocks
#define NEG075LN2 (-0.51986038542f)    // -0.75 * ln(2)

typedef float f32x4 __attribute__((ext_vector_type(4)));

__device__ __forceinline__ f32x4 ntload(const f32x4* p) {
    return __builtin_nontemporal_load(p);   // streaming read: nt cache hint
}

// ws layout (floats), every slot rewritten every call (no init needed):
//   [0      .. NBLK)    per-block c partial
//   [NBLK   .. 2*NBLK)  per-block r partial
//   [2*NBLK .. 3*NBLK)  per-block n partial

// One anchor's assignment + (if positive) GIoU + focal correction. Returns m.
__device__ __forceinline__ float phase1_anchor(
    int b, int a, bool valid,
    const float* __restrict__ cls, const float* __restrict__ reg,
    const float* __restrict__ anchors, const float* __restrict__ annb,
    float& c_acc, float& r_acc, float& n_acc)
{
    float mval = 0.0f;
    if (valid) {
        float4 anc = ((const float4*)anchors)[a];
        float ay1 = anc.x, ax1 = anc.y, ay2 = anc.z, ax2 = anc.w;
        float area_a = (ay2 - ay1) * (ax2 - ax1);
        float binter = 0.0f, bua = 1.0f;
        int   barg = 0;
        #pragma unroll
        for (int j = 0; j < M_ANN; ++j) {
            float bx1 = annb[j * 5 + 0], by1 = annb[j * 5 + 1];
            float bx2 = annb[j * 5 + 2], by2 = annb[j * 5 + 3];
            float iw = fmaxf(fminf(ax2, bx2) - fmaxf(ax1, bx1), 0.0f);
            float ih = fmaxf(fminf(ay2, by2) - fmaxf(ay1, by1), 0.0f);
            float inter = iw * ih;
            float ua = fmaxf(area_a + (bx2 - bx1) * (by2 - by1) - inter, 1e-8f);
            bool gt = inter * bua > binter * ua;   // iou_j > iou_best, division-free
            binter = gt ? inter : binter;
            bua    = gt ? ua    : bua;
            barg   = gt ? j     : barg;            // strict > keeps FIRST max
        }
        bool pos = binter >= 0.5f * bua;
        bool neg = binter <  0.4f * bua;
        mval = (pos || neg) ? NEG075LN2 : 0.0f;    // ignore band -> 0

        if (pos) {
            n_acc += 1.0f;
            int k = (int)annb[barg * 5 + 4];
            float cv = cls[((size_t)b * A_TOTAL + a) * C_CLS + k];
            float c  = fminf(fmaxf(cv, 5e-4f), 1.0f - 5e-4f);
            float omc = 1.0f - c;
            c_acc += 0.25f * omc * omc * (-__logf(c))
                   - 0.75f * c * c * (-__logf(omc));

            float4 rg = ((const float4*)reg)[(size_t)b * A_TOTAL + a];
            float ty = rg.x, tx = rg.y, th = rg.z, tw = rg.w;
            float aw = ax2 - ax1, ah = ay2 - ay1;
            float acx = ax1 + 0.5f * aw, acy = ay1 + 0.5f * ah;
            float pcx = tx * aw + acx, pcy = ty * ah + acy;
            float pw = __expf(tw) * aw, ph = __expf(th) * ah;
            float px1 = fmaxf(pcx - 0.5f * pw, 0.0f);
            float py1 = fmaxf(pcy - 0.5f * ph, 0.0f);
            float px2 = fmaxf(pcx + 0.5f * pw, 0.0f);
            float py2 = fmaxf(pcy + 0.5f * ph, 0.0f);
            float gx1 = fmaxf(annb[barg * 5 + 0], 0.0f);
            float gy1 = fmaxf(annb[barg * 5 + 1], 0.0f);
            float gx2 = fmaxf(annb[barg * 5 + 2], 0.0f);
            float gy2 = fmaxf(annb[barg * 5 + 3], 0.0f);
            float iw2 = fmaxf(fminf(px2, gx2) - fmaxf(px1, gx1), 0.0f);
            float ih2 = fmaxf(fminf(py2, gy2) - fmaxf(py1, gy1), 0.0f);
            float inter2 = iw2 * ih2;
            float area_p = fmaxf((px2 - px1) * (py2 - py1), 1e-6f);
            float area_g = fmaxf((gx2 - gx1) * (gy2 - gy1), 1e-6f);
            float uni = area_p + area_g - inter2;
            float iou2 = inter2 / (uni + 1e-7f);
            float wc = fmaxf(fmaxf(px2, gx2) - fminf(px1, gx1), 1e-6f);
            float hc = fmaxf(fmaxf(py2, gy2) - fminf(py1, gy1), 1e-6f);
            float area_c = wc * hc;
            float giou = fminf(fmaxf(iou2 - (area_c - uni) / (area_c + 1e-7f), -1.0f), 1.0f);
            r_acc += 1.0f - giou;
        }
    }
    return mval;
}

__global__ __launch_bounds__(THREADS) void focal_main_kernel(
    const float* __restrict__ cls,      // (B, A, C)
    const float* __restrict__ reg,      // (B, A, 4)
    const float* __restrict__ anchors,  // (A, 4)  [y1,x1,y2,x2]
    const float* __restrict__ ann,      // (B, M, 5) [x1,y1,x2,y2,class]
    float* __restrict__ ws)
{
    __shared__ float m_s[APB];
    __shared__ float red_c[4], red_r[4], red_n[4];

    const int b   = blockIdx.y;
    const int a0  = blockIdx.x * APB;
    const int tid = threadIdx.x;
    const int nA  = min(APB, A_TOTAL - a0);       // 512 or 192 (tail)
    const bool full = (nA == APB);
    const float* __restrict__ annb = ann + b * (M_ANN * 5);  // uniform -> s_load

    float r_acc = 0.0f, n_acc = 0.0f, c_acc = 0.0f;

    const f32x4* __restrict__ cp =
        (const f32x4*)(cls + ((size_t)b * A_TOTAL + a0) * C_CLS);

    // ---- Issue group-0 streaming loads FIRST (independent of phase 1) ----
    f32x4 v0, v1, v2, v3, v4, v5, v6, v7, v8, v9;
    if (full) {
        v0 = ntload(cp + tid);
        v1 = ntload(cp + tid + 256);
        v2 = ntload(cp + tid + 512);
        v3 = ntload(cp + tid + 768);
        v4 = ntload(cp + tid + 1024);
        v5 = ntload(cp + tid + 1280);
        v6 = ntload(cp + tid + 1536);
        v7 = ntload(cp + tid + 1792);
        v8 = ntload(cp + tid + 2048);
        v9 = ntload(cp + tid + 2304);
    }

    // ---- Phase 1: two anchors per thread (tid, tid+256) ----
    float m0 = phase1_anchor(b, a0 + tid, tid < nA,
                             cls, reg, anchors, annb, c_acc, r_acc, n_acc);
    float m1 = phase1_anchor(b, a0 + 256 + tid, 256 + tid < nA,
                             cls, reg, anchors, annb, c_acc, r_acc, n_acc);
    m_s[tid]       = m0;
    m_s[tid + 256] = m1;
    __syncthreads();

#define FOCAL4(v, l)                                                      \
    {                                                                     \
        float m_ = m_s[(unsigned)(l) / 20u];                              \
        float s_, c_;                                                     \
        c_ = fminf(fmaxf((v)[0], 5e-4f), 1.0f - 5e-4f);                   \
        s_ = c_ * c_ * __log2f(1.0f - c_);                                \
        c_ = fminf(fmaxf((v)[1], 5e-4f), 1.0f - 5e-4f);                   \
        s_ = fmaf(c_ * c_, __log2f(1.0f - c_), s_);                       \
        c_ = fminf(fmaxf((v)[2], 5e-4f), 1.0f - 5e-4f);                   \
        s_ = fmaf(c_ * c_, __log2f(1.0f - c_), s_);                       \
        c_ = fminf(fmaxf((v)[3], 5e-4f), 1.0f - 5e-4f);                   \
        s_ = fmaf(c_ * c_, __log2f(1.0f - c_), s_);                       \
        c_acc = fmaf(m_, s_, c_acc);                                      \
    }

    if (full) {
        // group 0: consume the pre-issued loads
        FOCAL4(v0, tid)
        FOCAL4(v1, tid + 256)
        FOCAL4(v2, tid + 512)
        FOCAL4(v3, tid + 768)
        FOCAL4(v4, tid + 1024)
        FOCAL4(v5, tid + 1280)
        FOCAL4(v6, tid + 1536)
        FOCAL4(v7, tid + 1792)
        FOCAL4(v8, tid + 2048)
        FOCAL4(v9, tid + 2304)
        // groups 1..3: 10 deep loads each, then consume
        #pragma unroll
        for (int g = 1; g < 4; ++g) {
            const int base = tid + g * 2560;
            v0 = ntload(cp + base);
            v1 = ntload(cp + base + 256);
            v2 = ntload(cp + base + 512);
            v3 = ntload(cp + base + 768);
            v4 = ntload(cp + base + 1024);
            v5 = ntload(cp + base + 1280);
            v6 = ntload(cp + base + 1536);
            v7 = ntload(cp + base + 1792);
            v8 = ntload(cp + base + 2048);
            v9 = ntload(cp + base + 2304);
            FOCAL4(v0, base)
            FOCAL4(v1, base + 256)
            FOCAL4(v2, base + 512)
            FOCAL4(v3, base + 768)
            FOCAL4(v4, base + 1024)
            FOCAL4(v5, base + 1280)
            FOCAL4(v6, base + 1536)
            FOCAL4(v7, base + 1792)
            FOCAL4(v8, base + 2048)
            FOCAL4(v9, base + 2304)
        }
    } else {
        // tail tile: 192 anchors -> 3840 float4, 15 strided iterations
        const int nf4 = nA * (C_CLS / 4);
        for (int l = tid; l < nf4; l += THREADS) {
            f32x4 v = ntload(cp + l);
            FOCAL4(v, l)
        }
    }
#undef FOCAL4

    // ---- Block reduction + NON-ATOMIC per-block slot write ----
    #pragma unroll
    for (int o = 32; o > 0; o >>= 1) {
        c_acc += __shfl_down(c_acc, o);
        r_acc += __shfl_down(r_acc, o);
        n_acc += __shfl_down(n_acc, o);
    }
    int wid = tid >> 6;
    if ((tid & 63) == 0) { red_c[wid] = c_acc; red_r[wid] = r_acc; red_n[wid] = n_acc; }
    __syncthreads();
    if (tid == 0) {
        const int slot = b * NBLK_X + blockIdx.x;
        ws[slot]            = red_c[0] + red_c[1] + red_c[2] + red_c[3];
        ws[NBLK + slot]     = red_r[0] + red_r[1] + red_r[2] + red_r[3];
        ws[2 * NBLK + slot] = red_n[0] + red_n[1] + red_n[2] + red_n[3];
    }
}

// One pass, 32 threads per image (8 images x 32 lanes = 256 threads).
__global__ __launch_bounds__(THREADS) void finalize_kernel(
    const float* __restrict__ ws, float* __restrict__ out)
{
    __shared__ float sc[B_IMG], sr[B_IMG], sn[B_IMG];
    const int tid    = threadIdx.x;
    const int img    = tid >> 5;        // 0..7
    const int lane32 = tid & 31;

    float pc = 0.0f, pr = 0.0f, pn = 0.0f;
    for (int i = lane32; i < NBLK_X; i += 32) {
        const int slot = img * NBLK_X + i;
        pc += ws[slot];
        pr += ws[NBLK + slot];
        pn += ws[2 * NBLK + slot];
    }
    #pragma unroll
    for (int o = 16; o > 0; o >>= 1) {
        pc += __shfl_down(pc, o, 32);
        pr += __shfl_down(pr, o, 32);
        pn += __shfl_down(pn, o, 32);
    }
    if (lane32 == 0) { sc[img] = pc; sr[img] = pr; sn[img] = pn; }
    __syncthreads();
    if (tid == 0) {
        float c_tot = 0.0f, r_tot = 0.0f;
        #pragma unroll
        for (int b = 0; b < B_IMG; ++b) {
            float ns = sn[b];
            c_tot += sc[b] / fmaxf(ns, 1.0f);
            r_tot += (ns > 0.0f) ? (sr[b] / fmaxf(ns, 1.0f)) : 0.0f;
        }
        c_tot *= (1.0f / B_IMG);
        r_tot *= (1.0f / B_IMG);
        out[0] = c_tot + r_tot;
        out[1] = c_tot;
        out[2] = r_tot;
    }
}

extern "C" void kernel_launch(void* const* d_in, const int* in_sizes, int n_in,
                              void* d_out, int out_size, void* d_ws, size_t ws_size,
                              hipStream_t stream) {
    const float* cls     = (const float*)d_in[0];
    const float* reg     = (const float*)d_in[1];
    const float* anchors = (const float*)d_in[2];
    const float* ann     = (const float*)d_in[3];
    float* ws  = (float*)d_ws;
    float* out = (float*)d_out;

    dim3 grid(NBLK_X, B_IMG);
    hipLaunchKernelGGL(focal_main_kernel, grid, dim3(THREADS), 0, stream,
                       cls, reg, anchors, ann, ws);
    hipLaunchKernelGGL(finalize_kernel, dim3(1), dim3(THREADS), 0, stream, ws, out);
}